// Round 15
// baseline (114.897 us; speedup 1.0000x reference)
//
#include <hip/hip_runtime.h>
#include <hip/hip_bf16.h>

// ClassBalancedSupConLoss, B=8192, D=128.
// loss_i = -(BASE/t_i)*[P_i - C_i*lse_i]/(C_i+eps)
//   P_i   = invt_i*(e_i.S_{c(i)} - ||e_i||^2)      (fp32 closed form)
//   C_i   = count_{c(i)} - 1
//   lse_i = invt_i*||e_i||^2 + ln(Z_i),  Z_i = sum_j exp2(v_ij - m_i),
//           m_i = invt_i*log2e*||e_i||^2 (fixed reference; exact identity)
// r15: (a) per-block j-PHASE ROTATION: blocks start the 16-step loop at
// different steps (fixed-m Z is a sum -> order-invariant) to break the
// phase-locked convoy (r9-r14: five k2 variants all ~30us at ~10% MfmaUtil
// while pipe models say ~8-11us -> duty-cycle limited, not pipe limited).
// (b) k3 FUSED into k2 via ticket: last 32 blocks (after spin to done==NB)
// compute the row-loss; 3 -> 2 dispatches. Zeroing moved to k0.
// k2 core = r14: global_load_lds width-16 DMA staging (no VGPR round-trip),
// W=1 lean, dual K-split MFMA chains, persistent -m init vector.
// LESSONS kept: r3/r6 dual chains; r10 prefetch load-bearing; r8 no
// min-waves VGPR cap; r12 no persistent acc generations.
// Ebf/Ebs in MFMA-fragment-tiled order (validated r4+):
//   (r,k) -> tile r>>5, chunk k>>4, lane (r&31)+((k>>3)&1)*32, e k&7.

#define B_ROWS 8192
#define D_DIM 128
#define NSPLIT 16
#define JRANGE (B_ROWS / NSPLIT)     // 512
#define NSTEPS (JRANGE / 32)         // 16
#define NBLOCKS (64 * NSPLIT)        // 1024
#define NWORKERS 32                  // k3 worker blocks (32*256 = 8192 rows)
#define BASE_TEMP 0.07f
#define LOG2E 1.4426950408889634f
#define LN2 0.6931471805599453f
#define FIX_SCALE 1048576.0f         // 2^20

typedef __bf16 bf16x8 __attribute__((ext_vector_type(8)));
typedef __bf16 bf16x4 __attribute__((ext_vector_type(4)));
typedef float floatx16 __attribute__((ext_vector_type(16)));
typedef unsigned long long u64;

__device__ __forceinline__ float class_invtemp(int lbl) {
    return (lbl == 0) ? 12.5f : ((lbl == 1) ? 20.0f : 10.0f);
}

__device__ __forceinline__ u64 fix64(float v) {
    return (u64)(long long)llrintf(v * FIX_SCALE);
}

// direct global->LDS DMA, 16B per lane; lds base must be wave-uniform
__device__ __forceinline__ void load_lds16(const __bf16* g, __bf16* l) {
    __builtin_amdgcn_global_load_lds(
        (const __attribute__((address_space(1))) void*)g,
        (__attribute__((address_space(3))) void*)l,
        16, 0, 0);
}

// ---- K0: single-pass cast->tiled Ebf/Ebs + norms + class partials ----
__global__ __launch_bounds__(256) void k0_prep(
        const float* __restrict__ E, const int* __restrict__ labels,
        __bf16* __restrict__ Ebf, __bf16* __restrict__ Ebs,
        float* __restrict__ nrm,
        float* __restrict__ Spart /*[256][3][128]*/,
        int* __restrict__ cntpart /*[256][4]*/,
        u64* __restrict__ zeroblk /*lossfix,validfix,done,done2*/) {
    const int blk = blockIdx.x;          // 256 blocks x 32 rows
    const int tid = threadIdx.x;
    const int row0 = blk * 32;

    if (blk == 0 && tid < 4) zeroblk[tid] = 0ull;   // tickets + accumulators

    __shared__ float4 red[3][256];       // 12 KB class partial reduce
    __shared__ int scnt[3];
    if (tid < 3) scnt[tid] = 0;

    float4 cls0 = {0.f, 0.f, 0.f, 0.f};
    float4 cls1 = {0.f, 0.f, 0.f, 0.f};
    float4 cls2 = {0.f, 0.f, 0.f, 0.f};

    const float4* src = reinterpret_cast<const float4*>(E + (size_t)row0 * D_DIM);
    #pragma unroll
    for (int p = 0; p < 4; ++p) {
        int idx = p * 256 + tid;         // 1024 float4 = 32 rows x 32 k4
        float4 v = src[idx];
        int r = idx >> 5, k4 = idx & 31;
        int R = row0 + r;
        int lab = labels[R];
        float sc = class_invtemp(lab) * LOG2E;
        int T = R >> 5;
        int l = (R & 31) + ((k4 >> 1) & 1) * 32;
        int c = k4 >> 2;
        size_t dst = (size_t)T * 4096 + c * 512 + l * 8 + (k4 & 1) * 4;
        bf16x4 o  = { (__bf16)v.x, (__bf16)v.y, (__bf16)v.z, (__bf16)v.w };
        bf16x4 os = { (__bf16)(v.x * sc), (__bf16)(v.y * sc),
                      (__bf16)(v.z * sc), (__bf16)(v.w * sc) };
        *reinterpret_cast<bf16x4*>(Ebf + dst) = o;
        *reinterpret_cast<bf16x4*>(Ebs + dst) = os;
        // norms: 32 consecutive lanes hold one full row
        float s = v.x * v.x + v.y * v.y + v.z * v.z + v.w * v.w;
        s += __shfl_xor(s, 1);  s += __shfl_xor(s, 2);  s += __shfl_xor(s, 4);
        s += __shfl_xor(s, 8);  s += __shfl_xor(s, 16);
        if ((tid & 31) == 0) nrm[R] = s;
        // class partials in registers (thread owns dims [4*k4, 4*k4+4))
        if (lab == 0) { cls0.x += v.x; cls0.y += v.y; cls0.z += v.z; cls0.w += v.w; }
        else if (lab == 1) { cls1.x += v.x; cls1.y += v.y; cls1.z += v.z; cls1.w += v.w; }
        else { cls2.x += v.x; cls2.y += v.y; cls2.z += v.z; cls2.w += v.w; }
    }
    red[0][tid] = cls0;
    red[1][tid] = cls1;
    red[2][tid] = cls2;
    if (tid < 32) atomicAdd(&scnt[labels[row0 + tid]], 1);   // LDS int: exact
    __syncthreads();

    if (tid < 128) {                     // d = tid; 8 contributors at k4=d>>2
        const int k4 = tid >> 2, comp = tid & 3;
        const float* rf = reinterpret_cast<const float*>(red);
        #pragma unroll
        for (int c = 0; c < 3; ++c) {
            float a = 0.f;
            #pragma unroll
            for (int w = 0; w < 8; ++w)
                a += rf[(c * 256 + k4 + 32 * w) * 4 + comp];
            Spart[((size_t)blk * 3 + c) * 128 + tid] = a;
        }
    }
    if (tid < 3) cntpart[blk * 4 + tid] = scnt[tid];
}

// ---- K2: DMA-staged A, phase-rotated j-loop, fused k3 via tickets ----
// grid (64 itiles, NSPLIT); block 256 = 4 waves; wave owns 32 i-cols.
__global__ __launch_bounds__(256) void k2_stats(
        const float* __restrict__ E,
        const __bf16* __restrict__ Ebf, const __bf16* __restrict__ Ebs,
        const int* __restrict__ labels, const float* __restrict__ nrm,
        float* __restrict__ part /*[NSPLIT][B]*/,
        const float* __restrict__ Spart, const int* __restrict__ cntpart,
        float* __restrict__ S /*[3*128]*/, float* __restrict__ counts /*[4]*/,
        u64* __restrict__ lossfix, u64* __restrict__ validfix,
        unsigned int* __restrict__ done, unsigned int* __restrict__ done2,
        float* __restrict__ out) {
    __shared__ __bf16 Ab[2][4096];       // 16 KB A-tile double buffer
    __shared__ float sS[384];
    __shared__ float rl[4];
    __shared__ int rv[4];
    __shared__ unsigned int tkt;

    const int tid = threadIdx.x;
    const int lane = tid & 63;
    const int wave = tid >> 6;
    const int itile = blockIdx.x;        // 0..63 (128 i-cols per block)
    const int split = blockIdx.y;        // 0..NSPLIT-1
    const int col = lane & 31;
    const int icol = itile * 128 + wave * 32 + col;

    const float negm = -class_invtemp(labels[icol]) * LOG2E * nrm[icol];

    // B frag (i side), pre-scaled (Ebs), register-resident (32 VGPR)
    const int iT = itile * 4 + wave;
    const __bf16* bbase = Ebs + (size_t)iT * 4096 + lane * 8;
    bf16x8 Bf[8];
    #pragma unroll
    for (int c = 0; c < 8; ++c)
        Bf[c] = *reinterpret_cast<const bf16x8*>(bbase + c * 512);

    // persistent C-in vector: a0 chain starts at -m with no per-step movs
    floatx16 init0;
    #pragma unroll
    for (int r = 0; r < 16; ++r) init0[r] = negm;

    // A tiles (j side): Ebf tiles [split*NSTEPS, +NSTEPS), 8 KB contiguous.
    // PHASE ROTATION: each block starts at its own step (sum is order-inv).
    const __bf16* abase = Ebf + (size_t)split * NSTEPS * 4096;
    const int woff = wave * 1024 + lane * 8;     // per-lane global offset
    const int s0 = (itile * 5 + split * 3) & (NSTEPS - 1);

    // prologue: DMA tile s0 into buffer 0
    load_lds16(abase + (size_t)s0 * 4096 + woff,       &Ab[0][wave * 1024]);
    load_lds16(abase + (size_t)s0 * 4096 + woff + 512, &Ab[0][wave * 1024 + 512]);
    __syncthreads();

    float Zacc[4];
    #pragma unroll
    for (int q = 0; q < 4; ++q) Zacc[q] = 0.f;

    for (int q = 0; q < NSTEPS; ++q) {
        // issue next-tile DMA FIRST (fire-and-forget)
        if (q + 1 < NSTEPS) {
            const int sn = (s0 + q + 1) & (NSTEPS - 1);
            const __bf16* g = abase + (size_t)sn * 4096 + woff;
            __bf16* l = &Ab[(q + 1) & 1][wave * 1024];
            load_lds16(g, l);
            load_lds16(g + 512, l + 512);
        }

        // ds_read current A fragments (conflict-free: lane-contiguous 16B)
        const __bf16* abuf = &Ab[q & 1][0];
        bf16x8 A[8];
        #pragma unroll
        for (int c = 0; c < 8; ++c)
            A[c] = *reinterpret_cast<const bf16x8*>(abuf + c * 512 + lane * 8);

        // dual K-split chains: a0 = -m + dot(k<64), a1 = dot(k>=64)
        floatx16 a1;
        #pragma unroll
        for (int r = 0; r < 16; ++r) a1[r] = 0.f;
        floatx16 a0 = __builtin_amdgcn_mfma_f32_32x32x16_bf16(A[0], Bf[0], init0, 0, 0, 0);
        a1 = __builtin_amdgcn_mfma_f32_32x32x16_bf16(A[4], Bf[4], a1, 0, 0, 0);
        a0 = __builtin_amdgcn_mfma_f32_32x32x16_bf16(A[1], Bf[1], a0, 0, 0, 0);
        a1 = __builtin_amdgcn_mfma_f32_32x32x16_bf16(A[5], Bf[5], a1, 0, 0, 0);
        a0 = __builtin_amdgcn_mfma_f32_32x32x16_bf16(A[2], Bf[2], a0, 0, 0, 0);
        a1 = __builtin_amdgcn_mfma_f32_32x32x16_bf16(A[6], Bf[6], a1, 0, 0, 0);
        a0 = __builtin_amdgcn_mfma_f32_32x32x16_bf16(A[3], Bf[3], a0, 0, 0, 0);
        a1 = __builtin_amdgcn_mfma_f32_32x32x16_bf16(A[7], Bf[7], a1, 0, 0, 0);

        #pragma unroll
        for (int p = 0; p < 4; ++p) {
            Zacc[p] += (__builtin_amdgcn_exp2f(a0[4 * p]     + a1[4 * p])
                      + __builtin_amdgcn_exp2f(a0[4 * p + 1] + a1[4 * p + 1]))
                     + (__builtin_amdgcn_exp2f(a0[4 * p + 2] + a1[4 * p + 2])
                      + __builtin_amdgcn_exp2f(a0[4 * p + 3] + a1[4 * p + 3]));
        }
        __syncthreads();
    }

    float Zt = (Zacc[0] + Zacc[1]) + (Zacc[2] + Zacc[3]);
    Zt += __shfl_xor(Zt, 32);            // lanes l, l+32 hold same i-col
    if (lane < 32)
        part[(size_t)split * B_ROWS + icol] = Zt;

    // ---- aux: S, counts (before this block's ticket) ----
    if (split == 0) {
        if (itile < 3 && tid < 128) {
            float a = 0.f;
            #pragma unroll 8
            for (int g = 0; g < 256; ++g)
                a += Spart[((size_t)g * 3 + itile) * 128 + tid];
            S[itile * 128 + tid] = a;
        } else if (itile == 3 && tid < 3) {
            int a = 0;
            #pragma unroll 8
            for (int g = 0; g < 256; ++g) a += cntpart[g * 4 + tid];
            counts[tid] = (float)a;
        }
    }

    // ---- ticket: last NWORKERS blocks run the fused row-loss (k3) ----
    __threadfence();
    if (tid == 0) tkt = atomicAdd(done, 1u);
    __syncthreads();
    const unsigned int t = tkt;
    if (t < NBLOCKS - NWORKERS) return;
    const int w = t - (NBLOCKS - NWORKERS);       // 0..NWORKERS-1

    // wait for ALL blocks (all are co-resident at 4/CU; non-workers exit,
    // freeing CUs, so stragglers always schedule -> no deadlock)
    if (tid == 0) { while (atomicAdd(done, 0u) < NBLOCKS) { __builtin_amdgcn_s_sleep(8); } }
    __syncthreads();

    if (tid < 128) {
        sS[tid]       = S[tid];
        sS[128 + tid] = S[128 + tid];
        sS[256 + tid] = S[256 + tid];
    }
    __syncthreads();

    const int i = w * 256 + tid;                  // 1 thread per row
    const int lab2 = labels[i];
    const float invt = class_invtemp(lab2);
    const float4* er = reinterpret_cast<const float4*>(E + (size_t)i * D_DIM);
    const float4* sr = reinterpret_cast<const float4*>(&sS[lab2 * 128]);
    float dotS = 0.f;
    #pragma unroll
    for (int k4 = 0; k4 < 32; ++k4) {
        float4 v = er[k4];
        float4 s = sr[k4];
        dotS += v.x * s.x + v.y * s.y + v.z * s.z + v.w * s.w;
    }
    float Zp = 0.f;
    #pragma unroll
    for (int p = 0; p < NSPLIT; ++p)
        Zp += part[(size_t)p * B_ROWS + i];

    const float nr = nrm[i];
    const float C = counts[lab2] - 1.0f;
    const float lse = invt * nr + LN2 * __builtin_amdgcn_logf(Zp);
    const float P_nat = invt * (dotS - nr);
    float loss = 0.f;
    int valid = 0;
    if (C > 0.f) {
        loss = -(BASE_TEMP * invt) * (P_nat - C * lse) / (C + 1e-8f);
        valid = 1;
    }
    #pragma unroll
    for (int off = 32; off; off >>= 1) {
        loss += __shfl_down(loss, off);
        valid += __shfl_down(valid, off);
    }
    if ((tid & 63) == 0) { rl[tid >> 6] = loss; rv[tid >> 6] = valid; }
    __syncthreads();
    if (tid == 0) {
        float bt = (rl[0] + rl[1]) + (rl[2] + rl[3]);
        int bv = (rv[0] + rv[1]) + (rv[2] + rv[3]);
        atomicAdd(lossfix, fix64(bt));
        atomicAdd(validfix, (u64)bv);
        __threadfence();
        unsigned int t2 = atomicAdd(done2, 1u);
        if (t2 == NWORKERS - 1) {        // last worker finalizes (deterministic)
            u64 L = atomicAdd(lossfix, 0ull);
            u64 V = atomicAdd(validfix, 0ull);
            double T = (double)(long long)L * (1.0 / (double)FIX_SCALE);
            double N = (double)(long long)V;
            out[0] = (N > 0.0) ? (float)(T / fmax(N, 1.0)) : 0.f;
        }
    }
}

extern "C" void kernel_launch(void* const* d_in, const int* in_sizes, int n_in,
                              void* d_out, int out_size, void* d_ws, size_t ws_size,
                              hipStream_t stream) {
    const float* E = (const float*)d_in[0];
    const int* labels = (const int*)d_in[1];
    float* out = (float*)d_out;
    char* ws = (char*)d_ws;

    // workspace layout (~6 MB)
    const size_t OFF_EBF   = 0;                        // 2 MB tiled bf16
    const size_t OFF_EBS   = (size_t)2 << 20;          // 2 MB tiled bf16 (scaled)
    const size_t OFF_NRM   = (size_t)4 << 20;          // 32 KB row norms
    const size_t OFF_SPART = OFF_NRM + 32768;          // 384 KB
    const size_t OFF_CNTP  = OFF_SPART + 393216;       // 4 KB
    const size_t OFF_S     = OFF_CNTP + 4096;          // 1.5 KB
    const size_t OFF_MISC  = OFF_S + 2048;             // counts + tickets
    const size_t OFF_PART  = (size_t)5 << 20;          // 512 KB (16 x 8192 f32)

    __bf16* Ebf = (__bf16*)(ws + OFF_EBF);
    __bf16* Ebs = (__bf16*)(ws + OFF_EBS);
    float* nrm = (float*)(ws + OFF_NRM);
    float* Spart = (float*)(ws + OFF_SPART);
    int* cntpart = (int*)(ws + OFF_CNTP);
    float* S = (float*)(ws + OFF_S);
    float* counts = (float*)(ws + OFF_MISC);           // 4 f32 (16 B)
    u64* zeroblk = (u64*)(ws + OFF_MISC + 32);         // 4 u64: loss,valid,done,done2
    u64* lossfix = zeroblk;
    u64* validfix = zeroblk + 1;
    unsigned int* done = (unsigned int*)(zeroblk + 2);
    unsigned int* done2 = (unsigned int*)(zeroblk + 3);
    float* part = (float*)(ws + OFF_PART);

    k0_prep<<<256, 256, 0, stream>>>(E, labels, Ebf, Ebs, nrm, Spart, cntpart,
                                     zeroblk);
    k2_stats<<<dim3(64, NSPLIT), 256, 0, stream>>>(
        E, Ebf, Ebs, labels, nrm, part, Spart, cntpart, S, counts,
        lossfix, validfix, done, done2, out);
}

// Round 16
// 47.349 us; speedup vs baseline: 2.4266x; 2.4266x over previous
//
#include <hip/hip_runtime.h>
#include <hip/hip_bf16.h>

// ClassBalancedSupConLoss, B=8192, D=128.
// loss_i = -(BASE/t_i)*[P_i - C_i*lse_i]/(C_i+eps)
//   P_i   = invt_i*(e_i.S_{c(i)} - ||e_i||^2)      (fp32 closed form)
//   C_i   = count_{c(i)} - 1
//   lse_i = invt_i*||e_i||^2 + ln(Z_i),  Z_i = sum_j exp2(v_ij - m_i),
//           m_i = invt_i*log2e*||e_i||^2 (fixed reference; exact identity)
// r16 = r14 + ONE change (clean A/B): per-block j-PHASE ROTATION.
// Blocks start the 16-step tile loop at s0=(5*itile+3*split)&15 to break
// the phase-locked convoy (r9-r14: five k2 variants all ~37us at ~10%
// MfmaUtil; staging/W/occupancy-invariant => duty-cycle limited).
// Fixed-m Z is a pure sum -> loop order irrelevant, bit-deterministic.
// r15 LESSON: tail-fusing the row-loss into k2 = 1/8-GPU serial tail
// (+70us). k3 stays a separate dispatch (true dispatch overhead ~6.5us).
// k2 core = r14: global_load_lds width-16 DMA staging, W=1 lean, dual
// K-split MFMA chains, persistent -m init vector.
// Ebf/Ebs in MFMA-fragment-tiled order (validated r4+):
//   (r,k) -> tile r>>5, chunk k>>4, lane (r&31)+((k>>3)&1)*32, e k&7.

#define B_ROWS 8192
#define D_DIM 128
#define NSPLIT 16
#define JRANGE (B_ROWS / NSPLIT)     // 512
#define NSTEPS (JRANGE / 32)         // 16
#define BASE_TEMP 0.07f
#define LOG2E 1.4426950408889634f
#define LN2 0.6931471805599453f
#define FIX_SCALE 1048576.0f         // 2^20

typedef __bf16 bf16x8 __attribute__((ext_vector_type(8)));
typedef __bf16 bf16x4 __attribute__((ext_vector_type(4)));
typedef float floatx16 __attribute__((ext_vector_type(16)));
typedef unsigned long long u64;

__device__ __forceinline__ float class_invtemp(int lbl) {
    return (lbl == 0) ? 12.5f : ((lbl == 1) ? 20.0f : 10.0f);
}

__device__ __forceinline__ u64 fix64(float v) {
    return (u64)(long long)llrintf(v * FIX_SCALE);
}

// direct global->LDS DMA, 16B per lane; lds base must be wave-uniform
__device__ __forceinline__ void load_lds16(const __bf16* g, __bf16* l) {
    __builtin_amdgcn_global_load_lds(
        (const __attribute__((address_space(1))) void*)g,
        (__attribute__((address_space(3))) void*)l,
        16, 0, 0);
}

// ---- K0: single-pass cast->tiled Ebf/Ebs + norms + class partials ----
__global__ __launch_bounds__(256) void k0_prep(
        const float* __restrict__ E, const int* __restrict__ labels,
        __bf16* __restrict__ Ebf, __bf16* __restrict__ Ebs,
        float* __restrict__ nrm,
        float* __restrict__ Spart /*[256][3][128]*/,
        int* __restrict__ cntpart /*[256][4]*/) {
    const int blk = blockIdx.x;          // 256 blocks x 32 rows
    const int tid = threadIdx.x;
    const int row0 = blk * 32;

    __shared__ float4 red[3][256];       // 12 KB class partial reduce
    __shared__ int scnt[3];
    if (tid < 3) scnt[tid] = 0;

    float4 cls0 = {0.f, 0.f, 0.f, 0.f};
    float4 cls1 = {0.f, 0.f, 0.f, 0.f};
    float4 cls2 = {0.f, 0.f, 0.f, 0.f};

    const float4* src = reinterpret_cast<const float4*>(E + (size_t)row0 * D_DIM);
    #pragma unroll
    for (int p = 0; p < 4; ++p) {
        int idx = p * 256 + tid;         // 1024 float4 = 32 rows x 32 k4
        float4 v = src[idx];
        int r = idx >> 5, k4 = idx & 31;
        int R = row0 + r;
        int lab = labels[R];
        float sc = class_invtemp(lab) * LOG2E;
        int T = R >> 5;
        int l = (R & 31) + ((k4 >> 1) & 1) * 32;
        int c = k4 >> 2;
        size_t dst = (size_t)T * 4096 + c * 512 + l * 8 + (k4 & 1) * 4;
        bf16x4 o  = { (__bf16)v.x, (__bf16)v.y, (__bf16)v.z, (__bf16)v.w };
        bf16x4 os = { (__bf16)(v.x * sc), (__bf16)(v.y * sc),
                      (__bf16)(v.z * sc), (__bf16)(v.w * sc) };
        *reinterpret_cast<bf16x4*>(Ebf + dst) = o;
        *reinterpret_cast<bf16x4*>(Ebs + dst) = os;
        // norms: 32 consecutive lanes hold one full row
        float s = v.x * v.x + v.y * v.y + v.z * v.z + v.w * v.w;
        s += __shfl_xor(s, 1);  s += __shfl_xor(s, 2);  s += __shfl_xor(s, 4);
        s += __shfl_xor(s, 8);  s += __shfl_xor(s, 16);
        if ((tid & 31) == 0) nrm[R] = s;
        // class partials in registers (thread owns dims [4*k4, 4*k4+4))
        if (lab == 0) { cls0.x += v.x; cls0.y += v.y; cls0.z += v.z; cls0.w += v.w; }
        else if (lab == 1) { cls1.x += v.x; cls1.y += v.y; cls1.z += v.z; cls1.w += v.w; }
        else { cls2.x += v.x; cls2.y += v.y; cls2.z += v.z; cls2.w += v.w; }
    }
    red[0][tid] = cls0;
    red[1][tid] = cls1;
    red[2][tid] = cls2;
    if (tid < 32) atomicAdd(&scnt[labels[row0 + tid]], 1);   // LDS int: exact
    __syncthreads();

    if (tid < 128) {                     // d = tid; 8 contributors at k4=d>>2
        const int k4 = tid >> 2, comp = tid & 3;
        const float* rf = reinterpret_cast<const float*>(red);
        #pragma unroll
        for (int c = 0; c < 3; ++c) {
            float a = 0.f;
            #pragma unroll
            for (int w = 0; w < 8; ++w)
                a += rf[(c * 256 + k4 + 32 * w) * 4 + comp];
            Spart[((size_t)blk * 3 + c) * 128 + tid] = a;
        }
    }
    if (tid < 3) cntpart[blk * 4 + tid] = scnt[tid];
}

// ---- K2: DMA-staged A, PHASE-ROTATED j-loop, dual K-split chains ----
// grid (64 itiles, NSPLIT); block 256 = 4 waves; wave owns 32 i-cols.
__global__ __launch_bounds__(256) void k2_stats(
        const __bf16* __restrict__ Ebf, const __bf16* __restrict__ Ebs,
        const int* __restrict__ labels, const float* __restrict__ nrm,
        float* __restrict__ part /*[NSPLIT][B]*/,
        const float* __restrict__ Spart, const int* __restrict__ cntpart,
        float* __restrict__ S /*[3*128]*/, float* __restrict__ counts /*[4]*/,
        u64* __restrict__ lossfix, u64* __restrict__ validfix,
        unsigned int* __restrict__ done) {
    __shared__ __bf16 Ab[2][4096];       // 16 KB A-tile double buffer

    const int tid = threadIdx.x;
    const int lane = tid & 63;
    const int wave = tid >> 6;
    const int itile = blockIdx.x;        // 0..63 (128 i-cols per block)
    const int split = blockIdx.y;        // 0..NSPLIT-1
    const int col = lane & 31;
    const int icol = itile * 128 + wave * 32 + col;

    const float negm = -class_invtemp(labels[icol]) * LOG2E * nrm[icol];

    // B frag (i side), pre-scaled (Ebs), register-resident (32 VGPR)
    const int iT = itile * 4 + wave;
    const __bf16* bbase = Ebs + (size_t)iT * 4096 + lane * 8;
    bf16x8 Bf[8];
    #pragma unroll
    for (int c = 0; c < 8; ++c)
        Bf[c] = *reinterpret_cast<const bf16x8*>(bbase + c * 512);

    // persistent C-in vector: a0 chain starts at -m with no per-step movs
    floatx16 init0;
    #pragma unroll
    for (int r = 0; r < 16; ++r) init0[r] = negm;

    // A tiles (j side): Ebf tiles [split*NSTEPS, +NSTEPS), 8 KB contiguous.
    // PHASE ROTATION: each block starts at its own step (Z sum = order-inv).
    const __bf16* abase = Ebf + (size_t)split * NSTEPS * 4096;
    const int woff = wave * 1024 + lane * 8;     // per-lane global offset
    const int s0 = (itile * 5 + split * 3) & (NSTEPS - 1);

    // prologue: DMA tile s0 into buffer 0
    load_lds16(abase + (size_t)s0 * 4096 + woff,       &Ab[0][wave * 1024]);
    load_lds16(abase + (size_t)s0 * 4096 + woff + 512, &Ab[0][wave * 1024 + 512]);
    __syncthreads();                              // drains vmcnt(0)

    float Zacc[4];
    #pragma unroll
    for (int q = 0; q < 4; ++q) Zacc[q] = 0.f;

    for (int q = 0; q < NSTEPS; ++q) {
        // issue next-tile DMA FIRST (fire-and-forget; lands before barrier)
        if (q + 1 < NSTEPS) {
            const int sn = (s0 + q + 1) & (NSTEPS - 1);
            const __bf16* g = abase + (size_t)sn * 4096 + woff;
            __bf16* l = &Ab[(q + 1) & 1][wave * 1024];
            load_lds16(g, l);
            load_lds16(g + 512, l + 512);
        }

        // ds_read current A fragments (conflict-free: lane-contiguous 16B)
        const __bf16* abuf = &Ab[q & 1][0];
        bf16x8 A[8];
        #pragma unroll
        for (int c = 0; c < 8; ++c)
            A[c] = *reinterpret_cast<const bf16x8*>(abuf + c * 512 + lane * 8);

        // dual K-split chains: a0 = -m + dot(k<64), a1 = dot(k>=64)
        floatx16 a1;
        #pragma unroll
        for (int r = 0; r < 16; ++r) a1[r] = 0.f;
        floatx16 a0 = __builtin_amdgcn_mfma_f32_32x32x16_bf16(A[0], Bf[0], init0, 0, 0, 0);
        a1 = __builtin_amdgcn_mfma_f32_32x32x16_bf16(A[4], Bf[4], a1, 0, 0, 0);
        a0 = __builtin_amdgcn_mfma_f32_32x32x16_bf16(A[1], Bf[1], a0, 0, 0, 0);
        a1 = __builtin_amdgcn_mfma_f32_32x32x16_bf16(A[5], Bf[5], a1, 0, 0, 0);
        a0 = __builtin_amdgcn_mfma_f32_32x32x16_bf16(A[2], Bf[2], a0, 0, 0, 0);
        a1 = __builtin_amdgcn_mfma_f32_32x32x16_bf16(A[6], Bf[6], a1, 0, 0, 0);
        a0 = __builtin_amdgcn_mfma_f32_32x32x16_bf16(A[3], Bf[3], a0, 0, 0, 0);
        a1 = __builtin_amdgcn_mfma_f32_32x32x16_bf16(A[7], Bf[7], a1, 0, 0, 0);

        #pragma unroll
        for (int p = 0; p < 4; ++p) {
            Zacc[p] += (__builtin_amdgcn_exp2f(a0[4 * p]     + a1[4 * p])
                      + __builtin_amdgcn_exp2f(a0[4 * p + 1] + a1[4 * p + 1]))
                     + (__builtin_amdgcn_exp2f(a0[4 * p + 2] + a1[4 * p + 2])
                      + __builtin_amdgcn_exp2f(a0[4 * p + 3] + a1[4 * p + 3]));
        }

        // one barrier per step (compiler folds vmcnt/lgkm drain into it)
        __syncthreads();
    }

    float Zt = (Zacc[0] + Zacc[1]) + (Zacc[2] + Zacc[3]);
    Zt += __shfl_xor(Zt, 32);            // lanes l, l+32 hold same i-col
    if (lane < 32)
        part[(size_t)split * B_ROWS + icol] = Zt;

    // ---- aux (ordered before k3 by stream): S, counts, ticket zero ----
    if (split == 0) {
        if (itile < 3 && tid < 128) {
            float a = 0.f;
            #pragma unroll 8
            for (int g = 0; g < 256; ++g)
                a += Spart[((size_t)g * 3 + itile) * 128 + tid];
            S[itile * 128 + tid] = a;
        } else if (itile == 3 && tid < 3) {
            int a = 0;
            #pragma unroll 8
            for (int g = 0; g < 256; ++g) a += cntpart[g * 4 + tid];
            counts[tid] = (float)a;
        } else if (itile == 4 && tid == 0) {
            *lossfix = 0ull;
            *validfix = 0ull;
            *done = 0u;
        }
    }
}

// ---- K3: per-row loss (8 thr/row), fixed-point accumulate + ticket ----
__global__ __launch_bounds__(256) void k3_rowloss(
        const float* __restrict__ E, const int* __restrict__ labels,
        const float* __restrict__ S, const float* __restrict__ counts,
        const float* __restrict__ nrm, const float* __restrict__ part,
        u64* __restrict__ lossfix, u64* __restrict__ validfix,
        unsigned int* __restrict__ done, float* __restrict__ out) {
    __shared__ float sS[384];
    const int tid = threadIdx.x;
    if (tid < 128) {
        sS[tid]       = S[tid];
        sS[128 + tid] = S[128 + tid];
        sS[256 + tid] = S[256 + tid];
    }
    __syncthreads();

    const int r = tid >> 3, g = tid & 7;       // 32 rows/block, 8 thr/row
    const int i = blockIdx.x * 32 + r;
    const int lab = labels[i];
    const float invt = class_invtemp(lab);

    const float4* er = reinterpret_cast<const float4*>(E + (size_t)i * D_DIM);
    const float4* sr = reinterpret_cast<const float4*>(&sS[lab * 128]);
    float dotS = 0.f;
    #pragma unroll
    for (int q = 0; q < 4; ++q) {
        float4 v = er[g * 4 + q];
        float4 s = sr[g * 4 + q];
        dotS += v.x * s.x + v.y * s.y + v.z * s.z + v.w * s.w;
    }
    float Zp = 0.f;
    #pragma unroll
    for (int p = 0; p < NSPLIT / 8; ++p)
        Zp += part[(size_t)(g + p * 8) * B_ROWS + i];

    #pragma unroll
    for (int off = 1; off < 8; off <<= 1) {
        dotS += __shfl_xor(dotS, off);
        Zp   += __shfl_xor(Zp, off);
    }

    float loss = 0.f;
    int valid = 0;
    if (g == 0) {
        const float nr = nrm[i];
        const float C = counts[lab] - 1.0f;
        const float lse = invt * nr + LN2 * __builtin_amdgcn_logf(Zp);
        const float P_nat = invt * (dotS - nr);
        if (C > 0.f) {
            loss = -(BASE_TEMP * invt) * (P_nat - C * lse) / (C + 1e-8f);
            valid = 1;
        }
    }
    loss += __shfl_down(loss, 8);   valid += __shfl_down(valid, 8);
    loss += __shfl_down(loss, 16);  valid += __shfl_down(valid, 16);
    loss += __shfl_down(loss, 32);  valid += __shfl_down(valid, 32);

    __shared__ float rl[4];
    __shared__ int rv[4];
    if ((tid & 63) == 0) { rl[tid >> 6] = loss; rv[tid >> 6] = valid; }
    __syncthreads();
    if (tid == 0) {
        float bt = (rl[0] + rl[1]) + (rl[2] + rl[3]);
        int bv = (rv[0] + rv[1]) + (rv[2] + rv[3]);
        atomicAdd(lossfix, fix64(bt));
        atomicAdd(validfix, (u64)bv);
        __threadfence();
        unsigned int t = atomicAdd(done, 1u);
        if (t == gridDim.x - 1) {     // last block finalizes (deterministic)
            u64 L = atomicAdd(lossfix, 0ull);
            u64 V = atomicAdd(validfix, 0ull);
            double T = (double)(long long)L * (1.0 / (double)FIX_SCALE);
            double N = (double)(long long)V;
            out[0] = (N > 0.0) ? (float)(T / fmax(N, 1.0)) : 0.f;
        }
    }
}

extern "C" void kernel_launch(void* const* d_in, const int* in_sizes, int n_in,
                              void* d_out, int out_size, void* d_ws, size_t ws_size,
                              hipStream_t stream) {
    const float* E = (const float*)d_in[0];
    const int* labels = (const int*)d_in[1];
    float* out = (float*)d_out;
    char* ws = (char*)d_ws;

    // workspace layout (~6 MB)
    const size_t OFF_EBF   = 0;                        // 2 MB tiled bf16
    const size_t OFF_EBS   = (size_t)2 << 20;          // 2 MB tiled bf16 (scaled)
    const size_t OFF_NRM   = (size_t)4 << 20;          // 32 KB row norms
    const size_t OFF_SPART = OFF_NRM + 32768;          // 384 KB
    const size_t OFF_CNTP  = OFF_SPART + 393216;       // 4 KB
    const size_t OFF_S     = OFF_CNTP + 4096;          // 1.5 KB
    const size_t OFF_MISC  = OFF_S + 2048;             // counts + ticket
    const size_t OFF_PART  = (size_t)5 << 20;          // 512 KB (16 x 8192 f32)

    __bf16* Ebf = (__bf16*)(ws + OFF_EBF);
    __bf16* Ebs = (__bf16*)(ws + OFF_EBS);
    float* nrm = (float*)(ws + OFF_NRM);
    float* Spart = (float*)(ws + OFF_SPART);
    int* cntpart = (int*)(ws + OFF_CNTP);
    float* S = (float*)(ws + OFF_S);
    float* counts = (float*)(ws + OFF_MISC);           // 4 f32
    u64* lossfix = (u64*)(ws + OFF_MISC + 16);
    u64* validfix = (u64*)(ws + OFF_MISC + 24);
    unsigned int* done = (unsigned int*)(ws + OFF_MISC + 32);
    float* part = (float*)(ws + OFF_PART);

    k0_prep<<<256, 256, 0, stream>>>(E, labels, Ebf, Ebs, nrm, Spart, cntpart);
    k2_stats<<<dim3(64, NSPLIT), 256, 0, stream>>>(
        Ebf, Ebs, labels, nrm, part, Spart, cntpart, S, counts,
        lossfix, validfix, done);
    k3_rowloss<<<256, 256, 0, stream>>>(E, labels, S, counts, nrm, part,
                                        lossfix, validfix, done, out);
}